// Round 5
// baseline (90.679 us; speedup 1.0000x reference)
//
#include <hip/hip_runtime.h>
#include <cmath>

#define T_STEPS 384
#define CH 64
#define NCH 6
#define WS 392   // replicated-table stride; 392 % 32 == 8 -> uniform bank spread

__device__ __forceinline__ float readlane_f(float v, int l) {
    return __int_as_float(__builtin_amdgcn_readlane(__float_as_int(v), l));
}

// One wave per neuron; lane l owns step cb+l of the current 64-step chunk.
// KEY CHANGE vs R4: the far-field Toeplitz passes for chunk c+1 (all g>=2,
// needing only deltas of chunks <= c-1) are computed INTERLEAVED with chunk
// c's 64-step serial loop (quarter per 16 steps), so the LDS gather hides in
// the step chain's stall slots instead of running sequentially after it.
// Only the g=1 pass (register window wgt1 over the just-finished chunk)
// remains in the prologue. Accumulation stays a single j-ascending fma chain
// (accN seeded, then g=1 appended) -> bit-identical FP to R4.
__global__ __launch_bounds__(64, 2)
void flif_kernel(const float* __restrict__ I_old, const float* __restrict__ W,
                 float* __restrict__ out, float cm1, float c2, float c3, int Stot)
{
    const int s    = blockIdx.x;
    const int lane = threadIdx.x;

    __shared__ __align__(16) float wrep[4 * WS];    // wrep[r][k] = rt[k+r], rt[i]=wr[384-i]
    __shared__ __align__(16) float lrep[4 * 128];   // lrep[r][k] = ltab[k+r], ltab[x]=wr[x-63]
    __shared__ __align__(16) float dbuf[T_STEPS];   // delta history

    const float* Irow = I_old + (size_t)s * T_STEPS;
    float Inext = Irow[lane];

    #pragma unroll
    for (int r = 0; r < 4; ++r) {
        for (int k = lane; k < WS; k += 64) {
            const int i = k + r;
            wrep[r * WS + k] = (i >= 1 && i <= 383) ? W[4615 + i] : 0.0f;   // rt[i]=wr[384-i]
        }
        for (int k = lane; k < 128; k += 64) {
            const int x = k + r;
            lrep[r * 128 + k] = (x >= 64 && x <= 126) ? W[5062 - x] : 0.0f; // ltab[x]=wr[x-63]
        }
    }
    __syncthreads();

    // near-field scatter window in registers: wloc[i] = wr[lane-i] (0 if lane<=i)
    float wloc[64];
    {
        const int r = lane & 3;
        const float* lp = lrep + r * 128 - r;             // lp[x] == ltab[x]
        #pragma unroll
        for (int i0 = 0; i0 < 64; i0 += 4) {
            const float4 f = *reinterpret_cast<const float4*>(lp + (lane + 60 - i0));
            wloc[i0 + 0] = f.w; wloc[i0 + 1] = f.z;
            wloc[i0 + 2] = f.y; wloc[i0 + 3] = f.x;
        }
    }

    // far-field per-lane base: wl[y] = rt[y - lane], 16B-aligned when (y%4)==0
    const int rsel = (-lane) & 3;
    const float* wl = wrep + rsel * WS - lane - rsel;

    // register weight window for chunk distance 1: wgt1[k] = wr[64+lane-k]
    float wgt1[64];
    #pragma unroll
    for (int k = 0; k < 64; k += 4) {
        const float4 f1 = *reinterpret_cast<const float4*>(wl + 320 + k);
        wgt1[k] = f1.x; wgt1[k + 1] = f1.y; wgt1[k + 2] = f1.z; wgt1[k + 3] = f1.w;
    }

    float* out_spk = out + (size_t)s * T_STEPS;
    float* out_trc = out + (size_t)Stot * T_STEPS + (size_t)s * T_STEPS;

    const float wr1n = -W[4998];          // -wr[1]

    float V = 0.0f, d = 0.0f, b = 0.0f, P = 0.0f;
    float accN = 0.0f;                    // far-field partial for the NEXT chunk (g>=2)

    #pragma unroll
    for (int c = 0; c < NCH; ++c) {
        const int cb = c * CH;
        const float Ic = Inext;
        if (c + 1 < NCH) Inext = Irow[cb + CH + lane];

        // ---- prologue: finish far field for THIS chunk ----
        // acc = accN (chunks <= c-2, computed during previous chunk's steps),
        // then append the g=1 pass (previous chunk's deltas, register weights).
        float acc = accN;
        accN = 0.0f;
        if (c >= 1) {
            const float* dp = dbuf + (c - 1) * CH;
            #pragma unroll
            for (int k = 0; k < 64; k += 4) {
                const float4 d4 = *reinterpret_cast<const float4*>(dp + k);  // broadcast
                acc = fmaf(d4.x, wgt1[k],     acc);
                acc = fmaf(d4.y, wgt1[k + 1], acc);
                acc = fmaf(d4.z, wgt1[k + 2], acc);
                acc = fmaf(d4.w, wgt1[k + 3], acc);
            }
        }

        float u = fmaf(c3, Ic, c2) - acc;
        const float Vs = V;
        float tc = 0.0f;

        // steady-state step: chain is t=fma(wr1n,d,P); d=t+b. Everything else slack.
        auto body = [&](int i) {
            const float t = fmaf(wr1n, d, P);            // t_i (uniform)
            d = t + b;                                   // d_i (uniform)   [chain]
            P = readlane_f(u, (i + 1) & 63);             // u_{i-1}[i+1], pre-scatter
            V = V + d;                                   // V_i
            const float rv = (V > -50.0f) ? -20.0f : 0.0f;
            b = fmaf(cm1, V, rv);                        // b_{i+1}
            u = fmaf(-wloc[i], d, u);                    // scatter d_i forward
            tc = (lane == i) ? V : tc;                   // capture trace
        };

        // quarter of next-chunk far field (passes cp=0..c-1, g=c+1-cp>=2),
        // interleaved between 16-step groups; single fma chain, cp/k ascending.
        const int nq = (c + 1 < NCH) ? c : 0;            // compile-time (loop unrolled)
        auto farq = [&](int q) {
            #pragma unroll
            for (int t2 = 0; t2 < nq * 4; ++t2) {
                const int qi = q * nq * 4 + t2;
                const int cp = qi >> 4;
                const int k  = (qi & 15) << 2;
                const float4 d4 = *reinterpret_cast<const float4*>(dbuf + cp * CH + k);      // broadcast
                const float4 w4 = *reinterpret_cast<const float4*>(wl + (384 - 64 * (c + 1 - cp)) + k); // per-lane b128
                accN = fmaf(d4.x, w4.x, accN);
                accN = fmaf(d4.y, w4.y, accN);
                accN = fmaf(d4.z, w4.z, accN);
                accN = fmaf(d4.w, w4.w, accN);
            }
        };

        if (c == 0) {
            // step 0: V_prev=0 -> spike, V_pre=-70, V_new=-90; delta masked out
            V = -90.0f;
            if (lane == 0) tc = V;
            // step 1: V1 rule (no memory); V=-90 -> no reset
            const float I1 = readlane_f(Ic, 1);
            const float V1 = fmaf(0.005f, (I1 / 0.025f) - V, V);
            const float d1 = V1 - V;
            P = readlane_f(u, 2);
            u = fmaf(-wloc[1], d1, u);
            if (lane == 1) tc = V1;
            V = V1;
            d = d1;
            const float rv = (V > -50.0f) ? -20.0f : 0.0f;
            b = fmaf(cm1, V, rv);
            #pragma unroll
            for (int i = 2; i < 16; ++i) body(i);
            // nq == 0 here; no far work
            #pragma unroll
            for (int q = 1; q < 4; ++q) {
                #pragma unroll
                for (int i = q * 16; i < q * 16 + 16; ++i) body(i);
            }
        } else {
            d = 0.0f;                                    // wr[1]*d_{cb-1} already in far field
            P = readlane_f(u, 0);
            #pragma unroll
            for (int q = 0; q < 4; ++q) {
                #pragma unroll
                for (int i = q * 16; i < q * 16 + 16; ++i) body(i);
                farq(q);
            }
        }

        // ---- chunk epilogue: reconstruct prev-V per lane -> spike, delta ----
        float prev = __shfl_up(tc, 1);
        if (lane == 0) prev = Vs;
        const float spk = (prev > -50.0f) ? 1.0f : 0.0f;
        float dd = tc - prev;
        if (c == 0 && lane == 0) dd = 0.0f;              // delta_0 excluded by reference
        dbuf[cb + lane] = dd;                            // wave-local, program-ordered
        out_spk[cb + lane] = spk;
        out_trc[cb + lane] = tc;
    }
}

extern "C" void kernel_launch(void* const* d_in, const int* in_sizes, int n_in,
                              void* d_out, int out_size, void* d_ws, size_t ws_size,
                              hipStream_t stream) {
    const float* I = (const float*)d_in[0];
    const float* W = (const float*)d_in[1];
    float* out = (float*)d_out;
    const int S = in_sizes[0] / T_STEPS;   // 2048

    const double COEF = std::pow(0.1, 0.15) * std::tgamma(1.85) / 0.5;
    const float c3  = (float)COEF;                     // COEF
    const float cm1 = (float)(-COEF * 0.025);          // c1 - 1 = -COEF*GL
    const float c2  = (float)(COEF * 0.025 * -70.0);   // COEF*GL*VL

    flif_kernel<<<S, 64, 0, stream>>>(I, W, out, cm1, c2, c3, S);
}

// Round 6
// 85.718 us; speedup vs baseline: 1.0579x; 1.0579x over previous
//
#include <hip/hip_runtime.h>
#include <cmath>

#define T_STEPS 384
#define CH 64
#define NCH 6
#define WS 392   // replica stride; 392 % 32 == 8 -> ascending per-lane b128 tiles all banks

__device__ __forceinline__ float readlane_f(float v, int l) {
    return __int_as_float(__builtin_amdgcn_readlane(__float_as_int(v), l));
}

// One wave per neuron; lane l owns step cb+l of the current 64-step chunk.
// Far field in AGE-ASCENDING form: mem_l = sum_m wt[l+m0]-window * delta
// broadcasts, with per-lane b128 weight reads at base (lane + m0) from a
// 4-shift replica (stride 392 == 8 mod 32 -> lanes 0..7 tile all 32 banks:
// ZERO conflicts, unlike the descending read used in R2-R5). Group order
// m0 = cb-4..0 with reversed in-group pairing reproduces R4's j-ascending
// fma chain BIT-IDENTICALLY. No register weight windows except wloc[64]
// (near-field scatter) -> ~100 VGPRs, no spill. Outer chunk loop rolled.
__global__ __launch_bounds__(64, 2)
void flif_kernel(const float* __restrict__ I_old, const float* __restrict__ W,
                 float* __restrict__ out, float cm1, float c2, float c3, int Stot)
{
    const int s    = blockIdx.x;
    const int lane = threadIdx.x;

    __shared__ __align__(16) float wtr[4 * WS];     // wtr[r][k] = wt[k+r], wt[i]=wr[i+1]=W[4998-i]
    __shared__ __align__(16) float lrep[4 * 128];   // lrep[r][k] = ltab[k+r], ltab[x]=wr[x-63]
    __shared__ __align__(16) float dbuf[T_STEPS];   // delta history

    const float* Irow = I_old + (size_t)s * T_STEPS;
    float Inext = Irow[lane];

    #pragma unroll
    for (int r = 0; r < 4; ++r) {
        for (int k = lane; k < WS; k += 64) {
            const int i = k + r;                     // wt[i] valid for i<=382
            wtr[r * WS + k] = (i <= 382) ? W[4998 - i] : 0.0f;
        }
        for (int k = lane; k < 128; k += 64) {
            const int x = k + r;
            lrep[r * 128 + k] = (x >= 64 && x <= 126) ? W[5062 - x] : 0.0f;
        }
    }
    __syncthreads();

    // near-field scatter window in registers: wloc[i] = wr[lane-i] (0 if lane<=i)
    float wloc[64];
    {
        const int r = lane & 3;
        const float* lp = lrep + r * 128 - r;        // lp[x] == ltab[x]
        #pragma unroll
        for (int i0 = 0; i0 < 64; i0 += 4) {
            const float4 f = *reinterpret_cast<const float4*>(lp + (lane + 60 - i0));
            wloc[i0 + 0] = f.w; wloc[i0 + 1] = f.z;
            wloc[i0 + 2] = f.y; wloc[i0 + 3] = f.x;
        }
    }

    // ascending per-lane weight base: wlp[m0 + q] = wt[lane + m0 + q], 16B-aligned
    const int rl = lane & 3;
    const float* wlp = wtr + rl * WS + (lane - rl);

    float* out_spk = out + (size_t)s * T_STEPS;
    float* out_trc = out + (size_t)Stot * T_STEPS + (size_t)s * T_STEPS;

    const float wr1n = -W[4998];          // -wr[1]

    float V = 0.0f, d = 0.0f, b = 0.0f, P = 0.0f;

    for (int c = 0; c < NCH; ++c) {
        const int cb = c * CH;
        const float Ic = Inext;
        if (c + 1 < NCH) Inext = Irow[cb + CH + lane];

        // ---- far field: acc = sum_{j<cb} delta_j * wr[(cb+lane)-j], j ascending ----
        // j = cb - m; group m0 = cb-4 .. 0 (desc) with in-group pairing
        // (d4.x,w4.w)(d4.y,w4.z)(d4.z,w4.y)(d4.w,w4.x) == j = cb-m0-4 .. cb-m0-1.
        float acc = 0.0f;
        #pragma unroll 4
        for (int m0 = cb - 4; m0 >= 0; m0 -= 4) {
            const float4 d4 = *reinterpret_cast<const float4*>(dbuf + (cb - m0 - 4)); // broadcast
            const float4 w4 = *reinterpret_cast<const float4*>(wlp + m0);             // per-lane, conflict-free
            acc = fmaf(d4.x, w4.w, acc);   // j = cb-m0-4, weight wr[lane+m0+4]
            acc = fmaf(d4.y, w4.z, acc);   // j = cb-m0-3
            acc = fmaf(d4.z, w4.y, acc);   // j = cb-m0-2
            acc = fmaf(d4.w, w4.x, acc);   // j = cb-m0-1, weight wr[lane+m0+1]
        }

        float u = fmaf(c3, Ic, c2) - acc;
        const float Vs = V;
        float tc = 0.0f;

        // steady-state step: chain is t=fma(wr1n,d,P); d=t+b. Everything else slack.
        auto body = [&](int i) {
            const float t = fmaf(wr1n, d, P);            // t_i (uniform)
            d = t + b;                                   // d_i (uniform)   [chain]
            P = readlane_f(u, (i + 1) & 63);             // u_{i-1}[i+1], pre-scatter
            V = V + d;                                   // V_i
            const float rv = (V > -50.0f) ? -20.0f : 0.0f;
            b = fmaf(cm1, V, rv);                        // b_{i+1}
            u = fmaf(-wloc[i], d, u);                    // scatter d_i forward
            tc = (lane == i) ? V : tc;                   // capture trace
        };

        if (c == 0) {
            // step 0: V_prev=0 -> spike, V_pre=-70, V_new=-90; delta masked out
            V = -90.0f;
            if (lane == 0) tc = V;
            // step 1: V1 rule (no memory); V=-90 -> no reset
            const float I1 = readlane_f(Ic, 1);
            const float V1 = fmaf(0.005f, (I1 / 0.025f) - V, V);
            const float d1 = V1 - V;
            P = readlane_f(u, 2);
            u = fmaf(-wloc[1], d1, u);
            if (lane == 1) tc = V1;
            V = V1;
            d = d1;
            const float rv = (V > -50.0f) ? -20.0f : 0.0f;
            b = fmaf(cm1, V, rv);
            #pragma unroll
            for (int i = 2; i < CH; ++i) body(i);
        } else {
            d = 0.0f;                                    // wr[1]*d_{cb-1} already in far field
            P = readlane_f(u, 0);
            #pragma unroll
            for (int i = 0; i < CH; ++i) body(i);
        }

        // ---- chunk epilogue: reconstruct prev-V per lane -> spike, delta ----
        float prev = __shfl_up(tc, 1);
        if (lane == 0) prev = Vs;
        const float spk = (prev > -50.0f) ? 1.0f : 0.0f;
        float dd = tc - prev;
        if (c == 0 && lane == 0) dd = 0.0f;              // delta_0 excluded by reference
        dbuf[cb + lane] = dd;                            // wave-local, program-ordered
        out_spk[cb + lane] = spk;
        out_trc[cb + lane] = tc;
    }
}

extern "C" void kernel_launch(void* const* d_in, const int* in_sizes, int n_in,
                              void* d_out, int out_size, void* d_ws, size_t ws_size,
                              hipStream_t stream) {
    const float* I = (const float*)d_in[0];
    const float* W = (const float*)d_in[1];
    float* out = (float*)d_out;
    const int S = in_sizes[0] / T_STEPS;   // 2048

    const double COEF = std::pow(0.1, 0.15) * std::tgamma(1.85) / 0.5;
    const float c3  = (float)COEF;                     // COEF
    const float cm1 = (float)(-COEF * 0.025);          // c1 - 1 = -COEF*GL
    const float c2  = (float)(COEF * 0.025 * -70.0);   // COEF*GL*VL

    flif_kernel<<<S, 64, 0, stream>>>(I, W, out, cm1, c2, c3, S);
}

// Round 7
// 85.093 us; speedup vs baseline: 1.0656x; 1.0073x over previous
//
#include <hip/hip_runtime.h>
#include <cmath>

#define T_STEPS 384
#define CH 64
#define NCH 6
#define WS 392   // replica stride; 392 % 32 == 8 -> ascending per-lane b128 tiles all banks

__device__ __forceinline__ float readlane_f(float v, int l) {
    return __int_as_float(__builtin_amdgcn_readlane(__float_as_int(v), l));
}

// Two waves per neuron (block=128). Wave 0: serial 64-step chunks (lane l owns
// step cb+l). Wave 1: computes the g>=2 far-field Toeplitz partial for chunk
// c+1 during wave 0's chunk c (it needs only deltas of chunks <= c-1, complete
// before chunk c starts), handed over via LDS with one __syncthreads per
// chunk. Wave 0 keeps only the g=1 pass. This doubles waves/SIMD (2 -> 4) to
// fill the step chain's stall slots and removes ~3/4 of the LDS gather from
// the critical wave. FP association is BIT-IDENTICAL to the previous kernel:
// partial = same m0-descending chain seeded 0; wave 0 appends m0=60..0.
// Output stores are buffered in registers and issued after the loop so the
// per-chunk barrier doesn't drain vmcnt on stores.
__global__ __launch_bounds__(128, 4)
void flif_kernel(const float* __restrict__ I_old, const float* __restrict__ W,
                 float* __restrict__ out, float cm1, float c2, float c3, int Stot)
{
    const int tid  = threadIdx.x;
    const int wid  = tid >> 6;
    const int lane = tid & 63;
    const int s    = blockIdx.x;

    __shared__ __align__(16) float wtr[4 * WS];     // wtr[r][k] = wt[k+r], wt[i]=wr[i+1]=W[4998-i]
    __shared__ __align__(16) float lrep[4 * 128];   // lrep[r][k] = ltab[k+r], ltab[x]=wr[x-63]
    __shared__ __align__(16) float dbuf[T_STEPS];   // delta history
    __shared__ float accs[2][CH];                   // far partial handoff (double-buffered)

    // cooperative table build (128 threads)
    for (int k = tid; k < 4 * WS; k += 128) {
        const int r = k / WS, kk = k - r * WS;
        const int i = kk + r;
        wtr[k] = (i <= 382) ? W[4998 - i] : 0.0f;
    }
    for (int k = tid; k < 512; k += 128) {
        const int r = k >> 7, kk = k & 127;
        const int x = kk + r;
        lrep[k] = (x >= 64 && x <= 126) ? W[5062 - x] : 0.0f;
    }
    ((float*)accs)[tid] = 0.0f;                      // partial(0)=partial(1)=0
    __syncthreads();

    // ascending per-lane weight base: wlp[m0+q] = wt[lane+m0+q], 16B-aligned, conflict-free
    const int rl = lane & 3;
    const float* wlp = wtr + rl * WS + (lane - rl);

    if (wid == 1) {
        // -------- far-field producer wave --------
        for (int c = 0; c < NCH; ++c) {
            if (c >= 1 && c <= 4) {
                // partial for target chunk C=c+1: m0 = CB-4 down to 64 (j ascending)
                const int CB = (c + 1) * CH;
                float acc = 0.0f;
                #pragma unroll 2
                for (int m0 = CB - 4; m0 >= 64; m0 -= 4) {
                    const float4 d4 = *reinterpret_cast<const float4*>(dbuf + (CB - m0 - 4)); // broadcast
                    const float4 w4 = *reinterpret_cast<const float4*>(wlp + m0);             // per-lane
                    acc = fmaf(d4.x, w4.w, acc);
                    acc = fmaf(d4.y, w4.z, acc);
                    acc = fmaf(d4.z, w4.y, acc);
                    acc = fmaf(d4.w, w4.x, acc);
                }
                accs[(c + 1) & 1][lane] = acc;
            }
            __syncthreads();
        }
        return;                                      // no stores from this wave
    }

    // -------- step-loop wave (wid == 0) --------
    const float* Irow = I_old + (size_t)s * T_STEPS;
    float Inext = Irow[lane];

    // near-field scatter window in registers: wloc[i] = wr[lane-i] (0 if lane<=i)
    float wloc[64];
    {
        const int r = lane & 3;
        const float* lp = lrep + r * 128 - r;        // lp[x] == ltab[x]
        #pragma unroll
        for (int i0 = 0; i0 < 64; i0 += 4) {
            const float4 f = *reinterpret_cast<const float4*>(lp + (lane + 60 - i0));
            wloc[i0 + 0] = f.w; wloc[i0 + 1] = f.z;
            wloc[i0 + 2] = f.y; wloc[i0 + 3] = f.x;
        }
    }

    const float wr1n = -W[4998];          // -wr[1]

    float V = 0.0f, d = 0.0f, b = 0.0f, P = 0.0f;
    float tcs[NCH], spks[NCH];            // buffered outputs (stored after loop)

    for (int c = 0; c < NCH; ++c) {
        const int cb = c * CH;
        const float Ic = Inext;
        if (c + 1 < NCH) Inext = Irow[cb + CH + lane];

        // ---- finish far field: partial (g>=2, from wave 1) + g=1 pass ----
        float acc = accs[c & 1][lane];
        if (c >= 1) {
            #pragma unroll 2
            for (int m0 = 60; m0 >= 0; m0 -= 4) {
                const float4 d4 = *reinterpret_cast<const float4*>(dbuf + (cb - m0 - 4)); // broadcast
                const float4 w4 = *reinterpret_cast<const float4*>(wlp + m0);             // per-lane
                acc = fmaf(d4.x, w4.w, acc);
                acc = fmaf(d4.y, w4.z, acc);
                acc = fmaf(d4.z, w4.y, acc);
                acc = fmaf(d4.w, w4.x, acc);
            }
        }

        float u = fmaf(c3, Ic, c2) - acc;
        const float Vs = V;
        float tc = 0.0f;

        // steady-state step: chain is t=fma(wr1n,d,P); d=t+b. Everything else slack.
        auto body = [&](int i) {
            const float t = fmaf(wr1n, d, P);            // t_i (uniform)
            d = t + b;                                   // d_i (uniform)   [chain]
            P = readlane_f(u, (i + 1) & 63);             // u_{i-1}[i+1], pre-scatter
            V = V + d;                                   // V_i
            const float rv = (V > -50.0f) ? -20.0f : 0.0f;
            b = fmaf(cm1, V, rv);                        // b_{i+1}
            u = fmaf(-wloc[i], d, u);                    // scatter d_i forward
            tc = (lane == i) ? V : tc;                   // capture trace
        };

        if (c == 0) {
            // step 0: V_prev=0 -> spike, V_pre=-70, V_new=-90; delta masked out
            V = -90.0f;
            if (lane == 0) tc = V;
            // step 1: V1 rule (no memory); V=-90 -> no reset
            const float I1 = readlane_f(Ic, 1);
            const float V1 = fmaf(0.005f, (I1 / 0.025f) - V, V);
            const float d1 = V1 - V;
            P = readlane_f(u, 2);
            u = fmaf(-wloc[1], d1, u);
            if (lane == 1) tc = V1;
            V = V1;
            d = d1;
            const float rv = (V > -50.0f) ? -20.0f : 0.0f;
            b = fmaf(cm1, V, rv);
            #pragma unroll
            for (int i = 2; i < CH; ++i) body(i);
        } else {
            d = 0.0f;                                    // wr[1]*d_{cb-1} already in far field
            P = readlane_f(u, 0);
            #pragma unroll
            for (int i = 0; i < CH; ++i) body(i);
        }

        // ---- chunk epilogue: prev-V per lane -> spike, delta; buffer outputs ----
        float prev = __shfl_up(tc, 1);
        if (lane == 0) prev = Vs;
        spks[c] = (prev > -50.0f) ? 1.0f : 0.0f;
        float dd = tc - prev;
        if (c == 0 && lane == 0) dd = 0.0f;              // delta_0 excluded by reference
        dbuf[cb + lane] = dd;
        tcs[c] = tc;
        __syncthreads();                                 // publish dbuf / consume accs
    }

    // ---- deferred global stores (off the barrier path) ----
    float* out_spk = out + (size_t)s * T_STEPS;
    float* out_trc = out + (size_t)Stot * T_STEPS + (size_t)s * T_STEPS;
    #pragma unroll
    for (int c = 0; c < NCH; ++c) {
        out_spk[c * CH + lane] = spks[c];
        out_trc[c * CH + lane] = tcs[c];
    }
}

extern "C" void kernel_launch(void* const* d_in, const int* in_sizes, int n_in,
                              void* d_out, int out_size, void* d_ws, size_t ws_size,
                              hipStream_t stream) {
    const float* I = (const float*)d_in[0];
    const float* W = (const float*)d_in[1];
    float* out = (float*)d_out;
    const int S = in_sizes[0] / T_STEPS;   // 2048

    const double COEF = std::pow(0.1, 0.15) * std::tgamma(1.85) / 0.5;
    const float c3  = (float)COEF;                     // COEF
    const float cm1 = (float)(-COEF * 0.025);          // c1 - 1 = -COEF*GL
    const float c2  = (float)(COEF * 0.025 * -70.0);   // COEF*GL*VL

    flif_kernel<<<S, 128, 0, stream>>>(I, W, out, cm1, c2, c3, S);
}